// Round 4
// baseline (197.053 us; speedup 1.0000x reference)
//
#include <hip/hip_runtime.h>
#include <hip/hip_bf16.h>
#include <math.h>

#define D 256
#define KNB 32
#define NEG_SLOPE 0.2f
#define GRID_AGG 512

using bfrag = __attribute__((ext_vector_type(8))) short;   // 8 bf16 (4 VGPR)
using ffrag = __attribute__((ext_vector_type(4))) float;   // 4 f32 acc

__device__ __forceinline__ unsigned short f2bf(float x) {
    __hip_bfloat16 h = __float2bfloat16(x);
    return *reinterpret_cast<unsigned short*>(&h);
}

// ---------------------------------------------------------------------------
// prep: blocks 0..63 convert W (f32 [256][256]) -> Wbf (bf16, same layout).
// block 64: w_src[f]=sum_o a_src[o]W[o][f], w_tgt likewise.
// ws layout (floats): [0..255]=w_src  [256..511]=w_tgt
//                     [512..33279]=Wbf (65536 bf16)
//                     [33280..53279]=scores_t (20000 f32)
//                     [53280.. ]=agg_bf (N*256 bf16)
// ---------------------------------------------------------------------------
__global__ __launch_bounds__(256) void prep_kernel(
    const float* __restrict__ W, const float* __restrict__ a_src,
    const float* __restrict__ a_tgt, float* __restrict__ ws)
{
    int t = threadIdx.x;
    int b = blockIdx.x;
    if (b < 64) {
        const float4* w4 = reinterpret_cast<const float4*>(W);
        float4 v = w4[b * 256 + t];
        ushort4 u;
        u.x = f2bf(v.x); u.y = f2bf(v.y); u.z = f2bf(v.z); u.w = f2bf(v.w);
        reinterpret_cast<ushort4*>(ws + 512)[b * 256 + t] = u;
    } else {
        float as = 0.f, at = 0.f;
        for (int o = 0; o < D; ++o) {
            float w = W[o * D + t];
            as = fmaf(a_src[o], w, as);
            at = fmaf(a_tgt[o], w, at);
        }
        ws[t]     = as;   // w_src
        ws[D + t] = at;   // w_tgt
    }
}

// ---------------------------------------------------------------------------
// scores_t[n] = nodes[n,:] . w_tgt   (one wave per node, 4 nodes/block)
// ---------------------------------------------------------------------------
__global__ __launch_bounds__(256) void scores_t_kernel(
    const float* __restrict__ nodes, const float* __restrict__ ws,
    float* __restrict__ scores_t, int N)
{
    int wid  = threadIdx.x >> 6;
    int lane = threadIdx.x & 63;
    int n = blockIdx.x * 4 + wid;
    if (n >= N) return;
    float4 v = reinterpret_cast<const float4*>(nodes + (size_t)n * D)[lane];
    float4 w = reinterpret_cast<const float4*>(ws + D)[lane];
    float s = v.x * w.x + v.y * w.y + v.z * w.z + v.w * w.w;
    #pragma unroll
    for (int off = 1; off < 64; off <<= 1) s += __shfl_xor(s, off);
    if (lane == 0) scores_t[n] = s;
}

// ---------------------------------------------------------------------------
// Persistent, double-buffered attention+aggregate.
// 512 blocks; block b handles nodes b, b+512, ... Tile (32x256 f32, 32KB)
// staged via global_load_lds (width 16) into LDS, double-buffered; next
// node's tile prefetched under current compute via counted vmcnt(8).
// Global source is chunk-XOR-pre-swizzled so LDS reads are conflict-free.
// LDS slot (r, chunk c) holds global chunk (c ^ (r&7)) of row r.
// ---------------------------------------------------------------------------
__global__ __launch_bounds__(256) void attn_agg_kernel(
    const float* __restrict__ neighbors, const float* __restrict__ ws,
    const float* __restrict__ scores_t, unsigned short* __restrict__ aggbf, int N)
{
    __shared__ __align__(16) float sn[2][KNB * D];   // 2 x 32 KB
    __shared__ float sp[KNB];

    const int t    = threadIdx.x;
    const int lane = t & 63;
    const int w    = t >> 6;
    const int b    = blockIdx.x;
    const int j    = t & 7;        // score phase: sub-lane within neighbor
    const int k    = t >> 3;       // score phase: neighbor index 0..31

    // per-thread w_src register chunks (score phase reads cols j*32 .. j*32+31)
    float4 wsv[8];
    #pragma unroll
    for (int m = 0; m < 8; ++m)
        wsv[m] = reinterpret_cast<const float4*>(ws)[j * 8 + m];

    const int nd = (N - 1 - b) / GRID_AGG + 1;   // nodes for this block

    // ---- issue first tile into buffer 0 ----
    {
        const float* gbase = neighbors + (size_t)b * (KNB * D);
        #pragma unroll
        for (int i = 0; i < 8; ++i) {
            int r = i * 4 + w;
            const float* src = gbase + r * D + ((lane ^ (r & 7)) << 2);
            __builtin_amdgcn_global_load_lds(
                (const __attribute__((address_space(1))) void*)src,
                (__attribute__((address_space(3))) void*)(&sn[0][r * D]),
                16, 0, 0);
        }
    }

    int cur = 0;
    for (int it = 0; it < nd; ++it) {
        const int n = b + it * GRID_AGG;
        const float st = scores_t[n];     // scalar (uniform) — issued before prefetch

        if (it + 1 < nd) {
            const float* gbase = neighbors + (size_t)(n + GRID_AGG) * (KNB * D);
            float* dbuf = &sn[cur ^ 1][0];
            #pragma unroll
            for (int i = 0; i < 8; ++i) {
                int r = i * 4 + w;
                const float* src = gbase + r * D + ((lane ^ (r & 7)) << 2);
                __builtin_amdgcn_global_load_lds(
                    (const __attribute__((address_space(1))) void*)src,
                    (__attribute__((address_space(3))) void*)(dbuf + r * D),
                    16, 0, 0);
            }
            asm volatile("s_waitcnt vmcnt(8)" ::: "memory");   // current tile done
        } else {
            asm volatile("s_waitcnt vmcnt(0)" ::: "memory");
        }
        __builtin_amdgcn_s_barrier();
        __builtin_amdgcn_sched_barrier(0);

        const float* buf = &sn[cur][0];

        // ---- score phase: thread (k,j) covers cols j*32..j*32+31 of row k ----
        float p = 0.f;
        #pragma unroll
        for (int m = 0; m < 8; ++m) {
            float4 v = *reinterpret_cast<const float4*>(
                &buf[k * D + (((j * 8 + m) ^ (k & 7)) << 2)]);
            p = fmaf(v.x, wsv[m].x,
                fmaf(v.y, wsv[m].y,
                fmaf(v.z, wsv[m].z,
                fmaf(v.w, wsv[m].w, p))));
        }
        p += __shfl_xor(p, 1);
        p += __shfl_xor(p, 2);
        p += __shfl_xor(p, 4);
        if (j == 0) {
            float e = p + st;
            e = (e >= 0.f) ? e : NEG_SLOPE * e;
            sp[k] = __expf(e);
        }
        asm volatile("s_waitcnt lgkmcnt(0)" ::: "memory");
        __builtin_amdgcn_s_barrier();
        __builtin_amdgcn_sched_barrier(0);

        // ---- aggregate phase: thread t owns output column t ----
        float sum = 0.f, acc = 0.f;
        #pragma unroll
        for (int kk = 0; kk < KNB; ++kk) {
            float pv = sp[kk];            // uniform broadcast
            sum += pv;
            acc = fmaf(pv, buf[kk * D + (((t >> 2) ^ (kk & 7)) << 2) + (t & 3)], acc);
        }
        aggbf[(size_t)n * D + t] = f2bf(acc / (sum + 1e-16f));

        __builtin_amdgcn_s_barrier();     // all reads of buf done before overwrite
        __builtin_amdgcn_sched_barrier(0);
        cur ^= 1;
    }
}

// ---------------------------------------------------------------------------
// out = elu(agg_bf @ Wbf^T + bias), f32 out. One wave per block, 16 rows.
// mfma_f32_16x16x32_bf16: D lane l: row=(l>>4)*4+reg, col=l&15
// ---------------------------------------------------------------------------
__global__ __launch_bounds__(64) void out_gemm_kernel(
    const unsigned short* __restrict__ aggbf,
    const unsigned short* __restrict__ wbf,
    const float* __restrict__ bias, float* __restrict__ out, int N)
{
    int l = threadIdx.x;
    int m0 = blockIdx.x * 16;
    if (m0 >= N) return;
    int lr = l & 15, lk = l >> 4;

    ffrag acc[16];
    #pragma unroll
    for (int nf = 0; nf < 16; ++nf) acc[nf] = ffrag{0.f, 0.f, 0.f, 0.f};

    #pragma unroll
    for (int ks = 0; ks < 8; ++ks) {
        bfrag a = *reinterpret_cast<const bfrag*>(
            aggbf + (size_t)(m0 + lr) * D + ks * 32 + lk * 8);
        #pragma unroll
        for (int nf = 0; nf < 16; ++nf) {
            bfrag b = *reinterpret_cast<const bfrag*>(
                wbf + (size_t)(nf * 16 + lr) * D + ks * 32 + lk * 8);
            acc[nf] = __builtin_amdgcn_mfma_f32_16x16x32_bf16(a, b, acc[nf], 0, 0, 0);
        }
    }

    #pragma unroll
    for (int nf = 0; nf < 16; ++nf) {
        int col = nf * 16 + lr;
        float bv = bias[col];
        #pragma unroll
        for (int r = 0; r < 4; ++r) {
            int m = m0 + lk * 4 + r;
            float x = acc[nf][r] + bv;
            x = (x > 0.f) ? x : expm1f(x);
            out[(size_t)m * D + col] = x;
        }
    }
}

// ---------------------------------------------------------------------------
extern "C" void kernel_launch(void* const* d_in, const int* in_sizes, int n_in,
                              void* d_out, int out_size, void* d_ws, size_t ws_size,
                              hipStream_t stream) {
    const float* nodes     = (const float*)d_in[0];
    const float* neighbors = (const float*)d_in[1];
    const float* W         = (const float*)d_in[2];
    const float* a_src     = (const float*)d_in[3];
    const float* a_tgt     = (const float*)d_in[4];
    const float* bias      = (const float*)d_in[5];
    float* out = (float*)d_out;
    float* ws  = (float*)d_ws;

    int N = in_sizes[0] / D;                                 // 20000
    unsigned short* wbf   = (unsigned short*)(ws + 512);     // 65536 bf16
    float* scores_t       = ws + 33280;                      // N f32
    unsigned short* aggbf = (unsigned short*)(ws + 53280);   // N*256 bf16

    hipLaunchKernelGGL(prep_kernel, dim3(65), dim3(256), 0, stream,
                       W, a_src, a_tgt, ws);
    hipLaunchKernelGGL(scores_t_kernel, dim3((N + 3) / 4), dim3(256), 0, stream,
                       nodes, ws, scores_t, N);
    hipLaunchKernelGGL(attn_agg_kernel, dim3(GRID_AGG), dim3(256), 0, stream,
                       neighbors, ws, scores_t, aggbf, N);
    hipLaunchKernelGGL(out_gemm_kernel, dim3(N / 16), dim3(64), 0, stream,
                       aggbf, wbf, bias, out, N);
}

// Round 5
// 185.916 us; speedup vs baseline: 1.0599x; 1.0599x over previous
//
#include <hip/hip_runtime.h>
#include <hip/hip_bf16.h>
#include <math.h>

#define D 256
#define KNB 32
#define NEG_SLOPE 0.2f

// ws layout (floats):
//   [0..255]       w_src
//   [256..511]     w_tgt
//   [512..33279]   Wbf (65536 bf16)
//   [33280..53279] scores_t (N f32)
//   [53280..69663] prep partials (32x256 src + 32x256 tgt)
//   [69664.. ]     agg_bf (N*256 bf16)
#define PART_OFF 53280
#define AGG_OFF  69664

using bfrag = __attribute__((ext_vector_type(8))) short;   // 8 bf16 (4 VGPR)
using ffrag = __attribute__((ext_vector_type(4))) float;   // 4 f32 acc

__device__ __forceinline__ unsigned short f2bf(float x) {
    __hip_bfloat16 h = __float2bfloat16(x);
    return *reinterpret_cast<unsigned short*>(&h);
}

// ---------------------------------------------------------------------------
// prep1: blocks 0..63 convert W -> bf16; blocks 64..95 compute 8-row partials
// of w_src/w_tgt with fully coalesced row reads.
// ---------------------------------------------------------------------------
__global__ __launch_bounds__(256) void prep1_kernel(
    const float* __restrict__ W, const float* __restrict__ a_src,
    const float* __restrict__ a_tgt, float* __restrict__ ws)
{
    int t = threadIdx.x;
    int b = blockIdx.x;
    if (b < 64) {
        float4 v = reinterpret_cast<const float4*>(W)[b * 256 + t];
        ushort4 u;
        u.x = f2bf(v.x); u.y = f2bf(v.y); u.z = f2bf(v.z); u.w = f2bf(v.w);
        reinterpret_cast<ushort4*>(ws + 512)[b * 256 + t] = u;
    } else {
        int bb = b - 64;               // 0..31, rows 8bb..8bb+7
        float ps = 0.f, pt = 0.f;
        #pragma unroll
        for (int oo = 0; oo < 8; ++oo) {
            int o = bb * 8 + oo;
            float wv = W[o * D + t];   // coalesced
            ps = fmaf(a_src[o], wv, ps);
            pt = fmaf(a_tgt[o], wv, pt);
        }
        ws[PART_OFF + bb * 256 + t]        = ps;
        ws[PART_OFF + 8192 + bb * 256 + t] = pt;
    }
}

// prep2: reduce the 32 partials -> w_src, w_tgt (1 block)
__global__ __launch_bounds__(256) void prep2_kernel(float* __restrict__ ws)
{
    int t = threadIdx.x;
    float s = 0.f, g = 0.f;
    #pragma unroll
    for (int j = 0; j < 32; ++j) {
        s += ws[PART_OFF + j * 256 + t];
        g += ws[PART_OFF + 8192 + j * 256 + t];
    }
    ws[t]     = s;   // w_src
    ws[D + t] = g;   // w_tgt
}

// ---------------------------------------------------------------------------
// scores_t[n] = nodes[n,:] . w_tgt   (one wave per node, 4 nodes/block)
// ---------------------------------------------------------------------------
__global__ __launch_bounds__(256) void scores_t_kernel(
    const float* __restrict__ nodes, const float* __restrict__ ws,
    float* __restrict__ scores_t, int N)
{
    int wid  = threadIdx.x >> 6;
    int lane = threadIdx.x & 63;
    int n = blockIdx.x * 4 + wid;
    if (n >= N) return;
    float4 v = reinterpret_cast<const float4*>(nodes + (size_t)n * D)[lane];
    float4 w = reinterpret_cast<const float4*>(ws + D)[lane];
    float s = v.x * w.x + v.y * w.y + v.z * w.z + v.w * w.w;
    #pragma unroll
    for (int off = 1; off < 64; off <<= 1) s += __shfl_xor(s, off);
    if (lane == 0) scores_t[n] = s;
}

// ---------------------------------------------------------------------------
// Register-resident attention + aggregate. One block per node, 256 threads.
// Thread t: wave w=t>>6, sub s=(t>>4)&3, c16=t&15; group g=t>>4 (0..15).
// Holds rows R=8w+2s, R+1 in 8 float4 regs (cols {m*16+c16}, m=0..3).
// Scores: 16-lane shfl reduce. Aggregation: pure-register fma; column
// partials combined through a small swizzled LDS exchange (2 rounds).
// DS ops per node-block ~650 cyc vs 3270 cyc HBM -> HBM-bound.
// ---------------------------------------------------------------------------
__global__ __launch_bounds__(256) void attn_agg_kernel(
    const float* __restrict__ neighbors, const float* __restrict__ ws,
    const float* __restrict__ scores_t, unsigned short* __restrict__ aggbf, int N)
{
    __shared__ __align__(16) float4 part[16][64];   // 16 KB
    __shared__ __align__(16) float4 part2[4][64];   //  4 KB
    __shared__ float wsum[4];

    const int t   = threadIdx.x;
    const int n   = blockIdx.x;
    const int w   = t >> 6;
    const int s   = (t >> 4) & 3;
    const int c16 = t & 15;
    const int g   = t >> 4;            // w*4 + s
    const int R   = 8 * w + 2 * s;

    // tile loads: v[j] = row R+(j>>2), float4-col (j&3)*16 + c16
    const float4* tile = reinterpret_cast<const float4*>(
        neighbors + (size_t)n * (KNB * D));
    float4 v[8];
    #pragma unroll
    for (int j = 0; j < 8; ++j)
        v[j] = tile[(R + (j >> 2)) * 64 + (j & 3) * 16 + c16];

    // w_src chunks for this thread's columns
    const float4* ws4 = reinterpret_cast<const float4*>(ws);
    float4 wsv[4];
    #pragma unroll
    for (int m = 0; m < 4; ++m) wsv[m] = ws4[m * 16 + c16];

    const float st = scores_t[n];

    // per-lane score partials for rows R (j=0..3) and R+1 (j=4..7)
    float pA = 0.f, pB = 0.f;
    #pragma unroll
    for (int m = 0; m < 4; ++m) {
        pA = fmaf(v[m].x, wsv[m].x, fmaf(v[m].y, wsv[m].y,
             fmaf(v[m].z, wsv[m].z, fmaf(v[m].w, wsv[m].w, pA))));
        pB = fmaf(v[4+m].x, wsv[m].x, fmaf(v[4+m].y, wsv[m].y,
             fmaf(v[4+m].z, wsv[m].z, fmaf(v[4+m].w, wsv[m].w, pB))));
    }
    // 16-lane reduce (stays within the sub-group)
    #pragma unroll
    for (int off = 1; off < 16; off <<= 1) {
        pA += __shfl_xor(pA, off);
        pB += __shfl_xor(pB, off);
    }

    float eA = pA + st; eA = (eA >= 0.f) ? eA : NEG_SLOPE * eA;
    float eB = pB + st; eB = (eB >= 0.f) ? eB : NEG_SLOPE * eB;
    float xA = __expf(eA);
    float xB = __expf(eB);

    // denominator: sum over this wave's 8 rows, then cross-wave via LDS
    float gs = xA + xB;
    gs += __shfl_xor(gs, 16);
    gs += __shfl_xor(gs, 32);
    if ((t & 63) == 0) wsum[w] = gs;

    // weighted column partials (pure register), write to swizzled LDS
    #pragma unroll
    for (int m = 0; m < 4; ++m) {
        float4 a;
        a.x = fmaf(xA, v[m].x, xB * v[4+m].x);
        a.y = fmaf(xA, v[m].y, xB * v[4+m].y);
        a.z = fmaf(xA, v[m].z, xB * v[4+m].z);
        a.w = fmaf(xA, v[m].w, xB * v[4+m].w);
        part[g][(m * 16 + c16) ^ ((g & 3) << 1)] = a;
    }
    __syncthreads();

    // round 1: thread (q = t&63, gg = t>>6) sums groups gg*4..gg*4+3
    {
        int q = t & 63, gg = t >> 6;
        float4 sum = part[gg * 4 + 0][q ^ 0];
        float4 b1  = part[gg * 4 + 1][q ^ 2];
        float4 b2  = part[gg * 4 + 2][q ^ 4];
        float4 b3  = part[gg * 4 + 3][q ^ 6];
        sum.x += b1.x + b2.x + b3.x;
        sum.y += b1.y + b2.y + b3.y;
        sum.z += b1.z + b2.z + b3.z;
        sum.w += b1.w + b2.w + b3.w;
        part2[gg][q] = sum;
    }
    __syncthreads();

    // round 2: wave 0 finalizes 64 column-quads
    if (t < 64) {
        float4 a0 = part2[0][t], a1 = part2[1][t], a2 = part2[2][t], a3 = part2[3][t];
        float inv = 1.f / (wsum[0] + wsum[1] + wsum[2] + wsum[3] + 1e-16f);
        float4 r;
        r.x = (a0.x + a1.x + a2.x + a3.x) * inv;
        r.y = (a0.y + a1.y + a2.y + a3.y) * inv;
        r.z = (a0.z + a1.z + a2.z + a3.z) * inv;
        r.w = (a0.w + a1.w + a2.w + a3.w) * inv;
        ushort4 u;
        u.x = f2bf(r.x); u.y = f2bf(r.y); u.z = f2bf(r.z); u.w = f2bf(r.w);
        reinterpret_cast<ushort4*>(aggbf + (size_t)n * D)[t] = u;
    }
}

// ---------------------------------------------------------------------------
// out = elu(agg_bf @ Wbf^T + bias), f32 out. One wave per block, 16 rows.
// mfma_f32_16x16x32_bf16: D lane l: row=(l>>4)*4+reg, col=l&15
// ---------------------------------------------------------------------------
__global__ __launch_bounds__(64) void out_gemm_kernel(
    const unsigned short* __restrict__ aggbf,
    const unsigned short* __restrict__ wbf,
    const float* __restrict__ bias, float* __restrict__ out, int N)
{
    int l = threadIdx.x;
    int m0 = blockIdx.x * 16;
    if (m0 >= N) return;
    int lr = l & 15, lk = l >> 4;

    ffrag acc[16];
    #pragma unroll
    for (int nf = 0; nf < 16; ++nf) acc[nf] = ffrag{0.f, 0.f, 0.f, 0.f};

    #pragma unroll
    for (int ks = 0; ks < 8; ++ks) {
        bfrag a = *reinterpret_cast<const bfrag*>(
            aggbf + (size_t)(m0 + lr) * D + ks * 32 + lk * 8);
        #pragma unroll
        for (int nf = 0; nf < 16; ++nf) {
            bfrag b = *reinterpret_cast<const bfrag*>(
                wbf + (size_t)(nf * 16 + lr) * D + ks * 32 + lk * 8);
            acc[nf] = __builtin_amdgcn_mfma_f32_16x16x32_bf16(a, b, acc[nf], 0, 0, 0);
        }
    }

    #pragma unroll
    for (int nf = 0; nf < 16; ++nf) {
        int col = nf * 16 + lr;
        float bv = bias[col];
        #pragma unroll
        for (int r = 0; r < 4; ++r) {
            int m = m0 + lk * 4 + r;
            float x = acc[nf][r] + bv;
            x = (x > 0.f) ? x : expm1f(x);
            out[(size_t)m * D + col] = x;
        }
    }
}

// ---------------------------------------------------------------------------
extern "C" void kernel_launch(void* const* d_in, const int* in_sizes, int n_in,
                              void* d_out, int out_size, void* d_ws, size_t ws_size,
                              hipStream_t stream) {
    const float* nodes     = (const float*)d_in[0];
    const float* neighbors = (const float*)d_in[1];
    const float* W         = (const float*)d_in[2];
    const float* a_src     = (const float*)d_in[3];
    const float* a_tgt     = (const float*)d_in[4];
    const float* bias      = (const float*)d_in[5];
    float* out = (float*)d_out;
    float* ws  = (float*)d_ws;

    int N = in_sizes[0] / D;                                  // 20000
    unsigned short* wbf   = (unsigned short*)(ws + 512);
    float* scores_t       = ws + 33280;
    unsigned short* aggbf = (unsigned short*)(ws + AGG_OFF);

    hipLaunchKernelGGL(prep1_kernel, dim3(96), dim3(256), 0, stream,
                       W, a_src, a_tgt, ws);
    hipLaunchKernelGGL(prep2_kernel, dim3(1), dim3(256), 0, stream, ws);
    hipLaunchKernelGGL(scores_t_kernel, dim3((N + 3) / 4), dim3(256), 0, stream,
                       nodes, ws, scores_t, N);
    hipLaunchKernelGGL(attn_agg_kernel, dim3(N), dim3(256), 0, stream,
                       neighbors, ws, scores_t, aggbf, N);
    hipLaunchKernelGGL(out_gemm_kernel, dim3(N / 16), dim3(64), 0, stream,
                       aggbf, wbf, bias, out, N);
}